// Round 12
// baseline (177.083 us; speedup 1.0000x reference)
//
#include <hip/hip_runtime.h>
#include <cmath>

// RestorationLoss = (1 - mean(SSIM(r_low, r_high))) + mean((r_low - r_high)^2)
// Separable 11x11 gaussian; 4 conv fields: mu1, mu2, S=conv(a^2+b^2), P=conv(ab).
// out = 1 + sum(d^2 - ssim_px)/N.
// R12 = R11 (95.6us) + two independent cuts:
//  (a) store-order SWIZZLE: slot s writes column 4cg+((s+(cg>>1))&3). R11/R5's
//      identical 7.67M conflict count proved conflicts live in the interleaved
//      b128 WRITES (lanes cg=0..7 start banks {0,16,..} = 4-way within the
//      8-lane LDS phase). Swizzle makes each store instruction hit 8 distinct
//      bank quads. Content unchanged.
//  (b) packed fp32: fields paired as float2 (mu1,mu2) and (S,P); taps contract
//      to v_pk_fma_f32 (2 FMA/instr) - we are issue-bound (65% VALUBusy vs
//      ~22us fundamental FMA), so halving tap instructions is real time.
// Frozen: 256 thr, launch_bounds(256,3) (R5/R7: tight caps spill; R10: no
// register arrays across barriers), TILE_H=16, R9 pipeline, rcp ssim,
// conditional-float4 edge loads, interleaved padded hbuf[26][65].

#define HH 512
#define WW 512
#define TILE_H 16
#define TILE_W 64
#define HB (TILE_H + 10)                          // 26 staged rows
#define LDW 65                                    // padded row: 65 float4s
#define NPLANES 48
#define CT (WW / TILE_W)                          // 8
#define RT (HH / TILE_H)                          // 32
#define NBLOCKS (NPLANES * RT * CT)               // 12288

typedef float f2 __attribute__((ext_vector_type(2)));

struct GW { float g[11]; };

__global__ __launch_bounds__(256, 3)              // VGPR cap ~170: allocator free
void ssim_main(const float* __restrict__ img1, const float* __restrict__ img2,
               float* __restrict__ partial, GW gw)
{
    __shared__ float4 hbuf[HB][LDW];              // interleaved (mu1,mu2,S,P): 27040 B
    __shared__ float red[4];

    const int tid   = threadIdx.x;
    const int bx    = blockIdx.x;
    const int by    = blockIdx.y;
    const int plane = blockIdx.z;
    const int row0  = by * TILE_H;
    const int col0  = bx * TILE_W;
    const float* p1 = img1 + (size_t)plane * (HH * WW);
    const float* p2 = img2 + (size_t)plane * (HH * WW);

    const int cg    = tid & 15;                   // col group: tile cols 4cg..4cg+3
    const int rs    = tid >> 4;                   // 0..15
    const int cbase = col0 + 4 * cg - 8;          // 20-float window, 16B aligned

    // 5 conditional float4 loads; OOB vectors become zeros (all OOB col spans
    // are float4-aligned: cbase%4==0 and limits 0/512 are multiples of 4)
    auto loadRow = [&](int grow, float4* x1, float4* x2) {
        const int growc = min(max(grow, 0), HH - 1);      // always in-bounds
        const float* r1 = p1 + (size_t)growc * WW;
        const float* r2 = p2 + (size_t)growc * WW;
        #pragma unroll
        for (int v = 0; v < 5; ++v) {
            const int c0 = cbase + 4 * v;
            if (c0 >= 0 && c0 + 4 <= WW) {
                x1[v] = *reinterpret_cast<const float4*>(r1 + c0);
                x2[v] = *reinterpret_cast<const float4*>(r2 + c0);
            } else {
                x1[v] = make_float4(0.f, 0.f, 0.f, 0.f);
                x2[v] = make_float4(0.f, 0.f, 0.f, 0.f);
            }
        }
    };

    // horizontal conv of one staged row -> interleaved hbuf[rl][col] (swizzled)
    auto convStore = [&](int rl, const float4* x1v, const float4* x2v) {
        const int   grow  = row0 - 5 + rl;
        const float rmask = (grow >= 0 && grow < HH) ? 1.f : 0.f;
        const float* x1 = reinterpret_cast<const float*>(x1v);
        const float* x2 = reinterpret_cast<const float*>(x2v);
        f2 acc_mu[4], acc_sp[4];
        #pragma unroll
        for (int i = 0; i < 4; ++i) { acc_mu[i] = (f2)0.f; acc_sp[i] = (f2)0.f; }
        #pragma unroll
        for (int e = 3; e <= 16; ++e) {           // out col i uses e = i+j+3
            float a = x1[e], b = x2[e];
            f2 ab = {a, b};
            f2 sp = {a * a + b * b, a * b};
            #pragma unroll
            for (int i = 0; i < 4; ++i) {
                int j = e - 3 - i;
                if (j >= 0 && j < 11) {
                    float w = gw.g[j];
                    acc_mu[i] = ab * w + acc_mu[i];   // v_pk_fma_f32
                    acc_sp[i] = sp * w + acc_sp[i];   // v_pk_fma_f32
                }
            }
        }
        // swizzled store order: slot s -> column 4cg + ((s + (cg>>1)) & 3).
        // Per 8-lane LDS phase, start banks become 8 distinct quads -> 0-conflict.
        // row-OOB rows contribute zero (all 4 fields vanish on zero inputs).
        #pragma unroll
        for (int s = 0; s < 4; ++s) {
            int i = (s + (cg >> 1)) & 3;
            hbuf[rl][4 * cg + i] =
                make_float4(acc_mu[i].x * rmask, acc_mu[i].y * rmask,
                            acc_sp[i].x * rmask, acc_sp[i].y * rmask);
        }
    };

    // ---- Phase 1: software-pipelined (R9): both rows' loads in flight ----
    {
        float4 xA1[5], xA2[5], xB1[5], xB2[5];
        loadRow(row0 - 5 + rs, xA1, xA2);         // rows 0..15
        loadRow(row0 + 11 + rs, xB1, xB2);        // rows 16..31 (clamped, safe)
        convStore(rs, xA1, xA2);                  // under B's load latency
        if (rs < 10)                              // only rows 16..25 staged
            convStore(rs + 16, xB1, xB2);
    }

    // ---- MSE pixel prefetch (no LDS dependence; consumed after barrier) ----
    const int tx = tid & 63;                      // column
    const int rg = tid >> 6;                      // 0..3 -> rows 4rg..4rg+3
    float mse_a[4], mse_b[4];
    #pragma unroll
    for (int p = 0; p < 4; ++p) {
        size_t off = (size_t)(row0 + rg * 4 + p) * WW + col0 + tx;
        mse_a[p] = p1[off];
        mse_b[p] = p2[off];
    }
    __syncthreads();

    // ---- Phase 2: vertical conv (14 b128 reads, pk taps) + ssim + mse ----
    float local = 0.f;
    {
        f2 rmu[4], rsp[4];
        #pragma unroll
        for (int p = 0; p < 4; ++p) { rmu[p] = (f2)0.f; rsp[p] = (f2)0.f; }
        #pragma unroll
        for (int j = 0; j < 14; ++j) {            // window rows rg*4 .. rg*4+13
            float4 w4 = hbuf[rg * 4 + j][tx];
            f2 mu = {w4.x, w4.y};
            f2 sp = {w4.z, w4.w};
            #pragma unroll
            for (int p = 0; p < 4; ++p) {
                int t = j - p;
                if (t >= 0 && t < 11) {
                    float w = gw.g[t];
                    rmu[p] = mu * w + rmu[p];     // v_pk_fma_f32
                    rsp[p] = sp * w + rsp[p];     // v_pk_fma_f32
                }
            }
        }
        const float C1c = 0.0001f, C2c = 0.0009f;
        #pragma unroll
        for (int p = 0; p < 4; ++p) {
            float mu1 = rmu[p].x, mu2 = rmu[p].y;
            float S   = rsp[p].x, P   = rsp[p].y;
            float m11 = mu1 * mu1, m22 = mu2 * mu2, m12 = mu1 * mu2;
            float num = (2.f * m12 + C1c) * (2.f * (P - m12) + C2c);
            float den = (m11 + m22 + C1c) * ((S - m11 - m22) + C2c);
            float inv = __builtin_amdgcn_rcpf(den);   // ~1ulp, fine vs 2.3e-2
            float d   = mse_a[p] - mse_b[p];
            local += d * d - num * inv;
        }
    }

    // ---- block reduce ----
    #pragma unroll
    for (int off = 32; off > 0; off >>= 1) local += __shfl_down(local, off);
    if ((tid & 63) == 0) red[tid >> 6] = local;
    __syncthreads();
    if (tid == 0) {
        int bid = (plane * RT + by) * CT + bx;
        partial[bid] = (red[0] + red[1]) + (red[2] + red[3]);
    }
}

__global__ __launch_bounds__(256)
void ssim_finish(const float* __restrict__ partial, float* __restrict__ out)
{
    __shared__ float red[256];
    float s = 0.f;
    #pragma unroll
    for (int i = 0; i < NBLOCKS / 256; ++i)       // 48 independent loads
        s += partial[i * 256 + threadIdx.x];
    red[threadIdx.x] = s;
    __syncthreads();
    for (int step = 128; step > 0; step >>= 1) {
        if ((int)threadIdx.x < step) red[threadIdx.x] += red[threadIdx.x + step];
        __syncthreads();
    }
    if (threadIdx.x == 0)
        out[0] = 1.0f + red[0] * (1.0f / 12582912.0f);
}

extern "C" void kernel_launch(void* const* d_in, const int* in_sizes, int n_in,
                              void* d_out, int out_size, void* d_ws, size_t ws_size,
                              hipStream_t stream)
{
    const float* r_low  = (const float*)d_in[0];
    const float* r_high = (const float*)d_in[1];
    float* out     = (float*)d_out;
    float* partial = (float*)d_ws;                       // 12288 floats = 48 KB

    GW gw;                                               // gaussian -> SGPRs
    {
        float s = 0.f;
        for (int i = 0; i < 11; ++i) {
            float c = (float)(i - 5);
            gw.g[i] = expf(-(c * c) / 4.5f);             // 2*sigma^2 = 4.5
            s += gw.g[i];
        }
        for (int i = 0; i < 11; ++i) gw.g[i] /= s;
    }

    dim3 grid(CT, RT, NPLANES);
    ssim_main<<<grid, dim3(256), 0, stream>>>(r_low, r_high, partial, gw);
    ssim_finish<<<1, dim3(256), 0, stream>>>(partial, out);
}